// Round 5
// baseline (665.168 us; speedup 1.0000x reference)
//
#include <hip/hip_runtime.h>
#include <stdint.h>

#define T_    100
#define B_    512
#define F_    784
#define FP_   800      // K for gemm0, zero-padded to a multiple of 32
#define H_    512
#define NOUT_ 10
#define R_    (T_*B_)      // 51200
#define BH    (B_*H_)      // 262144

typedef _Float16 f16x8 __attribute__((ext_vector_type(8)));
typedef float    f32x4 __attribute__((ext_vector_type(4)));

__device__ __forceinline__ void gload_lds16(const void* g, void* l) {
    __builtin_amdgcn_global_load_lds(
        (const __attribute__((address_space(1))) uint32_t*)g,
        (__attribute__((address_space(3))) uint32_t*)l, 16, 0, 0);
}

// ---------------------------------------------------------------------------
// W0 -> fp16 hi/lo split, zero-padded to Kp columns.
// ---------------------------------------------------------------------------
__global__ void convW_kernel(const float* __restrict__ W, _Float16* __restrict__ Wh,
                             _Float16* __restrict__ Wl, int K, int Kp, int n)
{
    int idx = blockIdx.x * 256 + threadIdx.x;
    if (idx >= n) return;
    int r = idx / Kp, k = idx - r * Kp;
    float v = (k < K) ? W[r * K + k] : 0.f;
    _Float16 h = (_Float16)v;
    Wh[idx] = h;
    Wl[idx] = (_Float16)(v - (float)h);
}

// ---------------------------------------------------------------------------
// X -> Xh/Xl fp16 hi/lo, padded 784 -> 800 cols. 8 elems per thread.
// ---------------------------------------------------------------------------
__global__ __launch_bounds__(256) void convX_kernel(
    const float* __restrict__ X, _Float16* __restrict__ Xh, _Float16* __restrict__ Xl)
{
    int idx = blockIdx.x * 256 + threadIdx.x;      // over 51200*100 chunks
    if (idx >= R_ * 100) return;
    int r = idx / 100, c8 = (idx - r * 100) * 8;
    f16x8 h, l;
    if (c8 + 8 <= F_) {
        float4 v0 = *(const float4*)(X + (size_t)r * F_ + c8);
        float4 v1 = *(const float4*)(X + (size_t)r * F_ + c8 + 4);
        float v[8] = {v0.x, v0.y, v0.z, v0.w, v1.x, v1.y, v1.z, v1.w};
#pragma unroll
        for (int j = 0; j < 8; j++) {
            _Float16 a = (_Float16)v[j];
            h[j] = a; l[j] = (_Float16)(v[j] - (float)a);
        }
    } else {
#pragma unroll
        for (int j = 0; j < 8; j++) { h[j] = (_Float16)0.f; l[j] = (_Float16)0.f; }
    }
    *(f16x8*)(Xh + (size_t)r * FP_ + c8) = h;
    *(f16x8*)(Xl + (size_t)r * FP_ + c8) = l;
}

// ---------------------------------------------------------------------------
// Wf[t,n,f] = alpha[t,f] * W1[n,f], split hi/lo.  Same fp32 mult + split as
// the old in-kernel writeB -> gemm1 result stays bit-identical.
// ---------------------------------------------------------------------------
__global__ __launch_bounds__(256) void foldW1_kernel(
    const float* __restrict__ W1, const float* __restrict__ alpha,
    _Float16* __restrict__ Wfh, _Float16* __restrict__ Wfl)
{
    int idx = blockIdx.x * 256 + threadIdx.x;      // 100 * 512 * 64
    if (idx >= 100 * 512 * 64) return;
    int t = idx >> 15, rem = idx & 32767, n = rem >> 6, f8 = (rem & 63) * 8;
    float4 w0 = *(const float4*)(W1 + (size_t)n * H_ + f8);
    float4 w1 = *(const float4*)(W1 + (size_t)n * H_ + f8 + 4);
    float4 a0 = *(const float4*)(alpha + t * H_ + f8);
    float4 a1 = *(const float4*)(alpha + t * H_ + f8 + 4);
    float w[8] = {w0.x, w0.y, w0.z, w0.w, w1.x, w1.y, w1.z, w1.w};
    float a[8] = {a0.x, a0.y, a0.z, a0.w, a1.x, a1.y, a1.z, a1.w};
    f16x8 h, l;
#pragma unroll
    for (int j = 0; j < 8; j++) {
        float p = a[j] * w[j];
        _Float16 q = (_Float16)p;
        h[j] = q; l[j] = (_Float16)(p - (float)q);
    }
    size_t o = ((size_t)t * H_ + n) * H_ + f8;
    *(f16x8*)(Wfh + o) = h;
    *(f16x8*)(Wfl + o) = l;
}

// ---------------------------------------------------------------------------
// GEMM0 (pure DMA): CUR = X@W0^T + b0.  128x128 tile, BK=32, all 4 operand
// halves via global_load_lds, 2-deep, counted vmcnt(8), 2 barriers/iter.
// ---------------------------------------------------------------------------
__global__ __launch_bounds__(256, 2) void gemm0_mfma(
    const _Float16* __restrict__ Xh, const _Float16* __restrict__ Xl,
    const _Float16* __restrict__ Wh, const _Float16* __restrict__ Wl,
    const float* __restrict__ bias, float* __restrict__ C)
{
    __shared__ _Float16 L[2 * 16384];   // per buf: Ah|Al|Bh|Bl, 4096 f16 each
    const int tid  = threadIdx.x;
    const int gl   = (blockIdx.x & 7) * 200 + (blockIdx.x >> 3);
    const int r0   = (gl >> 2) * 128;
    const int n0   = (gl & 3) * 128;
    const int lane = tid & 63;
    const int wm = (tid >> 7) & 1, wn = (tid >> 6) & 1;
    const int frow = lane & 15, fgrp = lane >> 4;

    const int drow = tid >> 2;
    const int dcol = (((tid & 3) ^ ((drow >> 1) & 3)) << 3);   // pre-swizzled src
    const _Float16* XhB = Xh + (size_t)(r0 + drow) * FP_ + dcol;
    const _Float16* XlB = Xl + (size_t)(r0 + drow) * FP_ + dcol;
    const _Float16* WhB = Wh + (size_t)(n0 + drow) * FP_ + dcol;
    const _Float16* WlB = Wl + (size_t)(n0 + drow) * FP_ + dcol;

    f32x4 acc[4][4];
#pragma unroll
    for (int i = 0; i < 4; i++)
#pragma unroll
        for (int j = 0; j < 4; j++) acc[i][j] = f32x4{0.f, 0.f, 0.f, 0.f};

    auto stage = [&](int buf, int kt) {     // 8 vmem ops
        _Float16* b = L + buf * 16384;
        gload_lds16(XhB + kt,            b + tid * 8);
        gload_lds16(XhB + 64 * FP_ + kt, b + 2048 + tid * 8);
        gload_lds16(XlB + kt,            b + 4096 + tid * 8);
        gload_lds16(XlB + 64 * FP_ + kt, b + 6144 + tid * 8);
        gload_lds16(WhB + kt,            b + 8192 + tid * 8);
        gload_lds16(WhB + 64 * FP_ + kt, b + 10240 + tid * 8);
        gload_lds16(WlB + kt,            b + 12288 + tid * 8);
        gload_lds16(WlB + 64 * FP_ + kt, b + 14336 + tid * 8);
    };

    stage(0, 0);
    for (int k = 0; k < 25; k++) {
        if (k < 24) {
            stage((k + 1) & 1, (k + 1) * 32);
            asm volatile("s_waitcnt vmcnt(8)" ::: "memory");
        } else {
            asm volatile("s_waitcnt vmcnt(0)" ::: "memory");
        }
        __builtin_amdgcn_sched_barrier(0);
        __builtin_amdgcn_s_barrier();
        __builtin_amdgcn_sched_barrier(0);

        const _Float16* bp = L + (k & 1) * 16384;
        f16x8 ah[4], al[4], bh[4], bl[4];
#pragma unroll
        for (int mi = 0; mi < 4; mi++) {
            int row = wm * 64 + mi * 16 + frow;
            int off = row * 32 + ((fgrp ^ ((row >> 1) & 3)) << 3);
            ah[mi] = *(const f16x8*)(bp + off);
            al[mi] = *(const f16x8*)(bp + 4096 + off);
        }
#pragma unroll
        for (int ni = 0; ni < 4; ni++) {
            int row = wn * 64 + ni * 16 + frow;
            int off = row * 32 + ((fgrp ^ ((row >> 1) & 3)) << 3);
            bh[ni] = *(const f16x8*)(bp + 8192 + off);
            bl[ni] = *(const f16x8*)(bp + 12288 + off);
        }
        __builtin_amdgcn_s_setprio(1);
#pragma unroll
        for (int mi = 0; mi < 4; mi++)
#pragma unroll
            for (int ni = 0; ni < 4; ni++) {
                acc[mi][ni] = __builtin_amdgcn_mfma_f32_16x16x32_f16(ah[mi], bh[ni], acc[mi][ni], 0, 0, 0);
                acc[mi][ni] = __builtin_amdgcn_mfma_f32_16x16x32_f16(ah[mi], bl[ni], acc[mi][ni], 0, 0, 0);
                acc[mi][ni] = __builtin_amdgcn_mfma_f32_16x16x32_f16(al[mi], bh[ni], acc[mi][ni], 0, 0, 0);
            }
        __builtin_amdgcn_s_setprio(0);
        __builtin_amdgcn_sched_barrier(0);
        __builtin_amdgcn_s_barrier();
        __builtin_amdgcn_sched_barrier(0);
    }

#pragma unroll
    for (int ni = 0; ni < 4; ni++) {
        int col = n0 + wn * 64 + ni * 16 + frow;
        float bv = bias[col];
#pragma unroll
        for (int mi = 0; mi < 4; mi++) {
            int rbase = r0 + wm * 64 + mi * 16 + fgrp * 4;
#pragma unroll
            for (int p = 0; p < 4; p++)
                C[(size_t)(rbase + p) * H_ + col] = acc[mi][ni][p] + bv;
        }
    }
}

// ---------------------------------------------------------------------------
// GEMM1 (pure DMA): CUR = Z @ Wf[t]^T + bW[t].  A exact fp16 spikes, B pre-
// folded hi/lo. LDS 48 KB -> 3 blocks/CU. vmcnt(6), 2 barriers/iter.
// ---------------------------------------------------------------------------
__global__ __launch_bounds__(256, 3) void gemm1_mfma(
    const _Float16* __restrict__ Zh, const _Float16* __restrict__ Wfh,
    const _Float16* __restrict__ Wfl, const float* __restrict__ bW,
    float* __restrict__ C)
{
    __shared__ _Float16 L[2 * 12288];   // per buf: Az | Bh | Bl, 4096 f16 each
    const int tid  = threadIdx.x;
    const int gl   = (blockIdx.x & 7) * 200 + (blockIdx.x >> 3);
    const int r0   = (gl >> 2) * 128;
    const int n0   = (gl & 3) * 128;
    const int tt   = gl >> 4;
    const int lane = tid & 63;
    const int wm = (tid >> 7) & 1, wn = (tid >> 6) & 1;
    const int frow = lane & 15, fgrp = lane >> 4;

    const int drow = tid >> 2;
    const int dcol = (((tid & 3) ^ ((drow >> 1) & 3)) << 3);
    const _Float16* ZhB = Zh + (size_t)(r0 + drow) * H_ + dcol;
    const _Float16* WfhB = Wfh + ((size_t)tt * H_ + n0 + drow) * H_ + dcol;
    const _Float16* WflB = Wfl + ((size_t)tt * H_ + n0 + drow) * H_ + dcol;

    f32x4 acc[4][4];
#pragma unroll
    for (int i = 0; i < 4; i++)
#pragma unroll
        for (int j = 0; j < 4; j++) acc[i][j] = f32x4{0.f, 0.f, 0.f, 0.f};

    auto stage = [&](int buf, int kt) {     // 6 vmem ops
        _Float16* b = L + buf * 12288;
        gload_lds16(ZhB + kt,            b + tid * 8);
        gload_lds16(ZhB + 64 * H_ + kt,  b + 2048 + tid * 8);
        gload_lds16(WfhB + kt,           b + 4096 + tid * 8);
        gload_lds16(WfhB + 64 * H_ + kt, b + 6144 + tid * 8);
        gload_lds16(WflB + kt,           b + 8192 + tid * 8);
        gload_lds16(WflB + 64 * H_ + kt, b + 10240 + tid * 8);
    };

    stage(0, 0);
    for (int k = 0; k < 16; k++) {
        if (k < 15) {
            stage((k + 1) & 1, (k + 1) * 32);
            asm volatile("s_waitcnt vmcnt(6)" ::: "memory");
        } else {
            asm volatile("s_waitcnt vmcnt(0)" ::: "memory");
        }
        __builtin_amdgcn_sched_barrier(0);
        __builtin_amdgcn_s_barrier();
        __builtin_amdgcn_sched_barrier(0);

        const _Float16* bp = L + (k & 1) * 12288;
        f16x8 az[4], bh[4], bl[4];
#pragma unroll
        for (int mi = 0; mi < 4; mi++) {
            int row = wm * 64 + mi * 16 + frow;
            int off = row * 32 + ((fgrp ^ ((row >> 1) & 3)) << 3);
            az[mi] = *(const f16x8*)(bp + off);
        }
#pragma unroll
        for (int ni = 0; ni < 4; ni++) {
            int row = wn * 64 + ni * 16 + frow;
            int off = row * 32 + ((fgrp ^ ((row >> 1) & 3)) << 3);
            bh[ni] = *(const f16x8*)(bp + 4096 + off);
            bl[ni] = *(const f16x8*)(bp + 8192 + off);
        }
        __builtin_amdgcn_s_setprio(1);
#pragma unroll
        for (int mi = 0; mi < 4; mi++)
#pragma unroll
            for (int ni = 0; ni < 4; ni++) {
                acc[mi][ni] = __builtin_amdgcn_mfma_f32_16x16x32_f16(az[mi], bh[ni], acc[mi][ni], 0, 0, 0);
                acc[mi][ni] = __builtin_amdgcn_mfma_f32_16x16x32_f16(az[mi], bl[ni], acc[mi][ni], 0, 0, 0);
            }
        __builtin_amdgcn_s_setprio(0);
        __builtin_amdgcn_sched_barrier(0);
        __builtin_amdgcn_s_barrier();
        __builtin_amdgcn_sched_barrier(0);
    }

#pragma unroll
    for (int ni = 0; ni < 4; ni++) {
        int col = n0 + wn * 64 + ni * 16 + frow;
        float bv = bW[tt * H_ + col];
#pragma unroll
        for (int mi = 0; mi < 4; mi++) {
            int rbase = r0 + wm * 64 + mi * 16 + fgrp * 4;
#pragma unroll
            for (int p = 0; p < 4; p++)
                C[(size_t)(rbase + p) * H_ + col] = acc[mi][ni][p] + bv;
        }
    }
}

// ======================= round-4 fallback GEMMs (verified) =================
__global__ __launch_bounds__(256, 2) void gemm0_old(
    const float* __restrict__ X, const _Float16* __restrict__ Wh,
    const _Float16* __restrict__ Wl, const float* __restrict__ bias,
    float* __restrict__ C)
{
    __shared__ _Float16 L[40960];
    const int tid  = threadIdx.x;
    const int gl   = (blockIdx.x & 7) * 200 + (blockIdx.x >> 3);
    const int r0   = (gl >> 2) * 128;
    const int n0   = (gl & 3) * 128;
    const int lane = tid & 63;
    const int wm = (tid >> 7) & 1, wn = (tid >> 6) & 1;
    const int frow = lane & 15, fgrp = lane >> 4;
    const int brow = tid >> 2;
    const int bcol = (((tid & 3) ^ ((brow >> 1) & 3)) << 3);
    const _Float16* WhB = Wh + (size_t)(n0 + brow) * FP_ + bcol;
    const _Float16* WlB = Wl + (size_t)(n0 + brow) * FP_ + bcol;
    const int arow = tid >> 1, ahalf = tid & 1;
    const float* Xb = X + (size_t)(r0 + arow) * F_ + ahalf * 16;
    const int aoff = arow * 32;
    const int ac0  = (((ahalf * 2)     ^ ((arow >> 1) & 3)) << 3);
    const int ac1  = (((ahalf * 2 + 1) ^ ((arow >> 1) & 3)) << 3);
    f32x4 acc[4][4];
#pragma unroll
    for (int i = 0; i < 4; i++)
#pragma unroll
        for (int j = 0; j < 4; j++) acc[i][j] = f32x4{0.f, 0.f, 0.f, 0.f};
    auto stageB = [&](int sbuf, int kt) {
        _Float16* dh = L + 16384 + sbuf * 8192;
        _Float16* dl = dh + 4096;
        gload_lds16(WhB + kt,            dh + tid * 8);
        gload_lds16(WhB + 64 * FP_ + kt, dh + 2048 + tid * 8);
        gload_lds16(WlB + kt,            dl + tid * 8);
        gload_lds16(WlB + 64 * FP_ + kt, dl + 2048 + tid * 8);
    };
    auto loadA = [&](float4 (&xa)[4], int kt) {
#pragma unroll
        for (int j = 0; j < 4; j++) {
            int c = kt + ahalf * 16 + j * 4;
            xa[j] = (c < F_) ? *(const float4*)(Xb + kt + j * 4)
                             : make_float4(0.f, 0.f, 0.f, 0.f);
        }
    };
    auto writeA = [&](int abuf, const float4 (&xa)[4]) {
        _Float16* dh = L + abuf * 8192;
        _Float16* dl = dh + 4096;
        const float* v = (const float*)xa;
        f16x8 h0, l0, h1, l1;
#pragma unroll
        for (int j = 0; j < 8; j++) {
            _Float16 a = (_Float16)v[j];
            h0[j] = a; l0[j] = (_Float16)(v[j] - (float)a);
            _Float16 b = (_Float16)v[8 + j];
            h1[j] = b; l1[j] = (_Float16)(v[8 + j] - (float)b);
        }
        *(f16x8*)(dh + aoff + ac0) = h0;
        *(f16x8*)(dh + aoff + ac1) = h1;
        *(f16x8*)(dl + aoff + ac0) = l0;
        *(f16x8*)(dl + aoff + ac1) = l1;
    };
    float4 R0[4], R1[4];
    stageB(0, 0); stageB(1, 32); loadA(R0, 0); loadA(R1, 32); writeA(0, R0);
    asm volatile("s_waitcnt lgkmcnt(0)" ::: "memory");
    __builtin_amdgcn_sched_barrier(0);
    __builtin_amdgcn_s_barrier();
    __builtin_amdgcn_sched_barrier(0);
    auto body = [&](int k, int rbuf, int sbuf, float4 (&Rl)[4], float4 (&Rw)[4],
                    bool pf, bool dw) {
        if (pf) { stageB(sbuf, (k + 2) * 32); loadA(Rl, (k + 2) * 32); }
        const _Float16* Ab = L + (k & 1) * 8192;
        const _Float16* Bb = L + 16384 + rbuf * 8192;
        f16x8 ah[4], al[4], bh[4], bl[4];
#pragma unroll
        for (int mi = 0; mi < 4; mi++) {
            int row = wm * 64 + mi * 16 + frow;
            int off = row * 32 + ((fgrp ^ ((row >> 1) & 3)) << 3);
            ah[mi] = *(const f16x8*)(Ab + off);
            al[mi] = *(const f16x8*)(Ab + 4096 + off);
        }
#pragma unroll
        for (int ni = 0; ni < 4; ni++) {
            int row = wn * 64 + ni * 16 + frow;
            int off = row * 32 + ((fgrp ^ ((row >> 1) & 3)) << 3);
            bh[ni] = *(const f16x8*)(Bb + off);
            bl[ni] = *(const f16x8*)(Bb + 4096 + off);
        }
        __builtin_amdgcn_s_setprio(1);
#pragma unroll
        for (int mi = 0; mi < 4; mi++)
#pragma unroll
            for (int ni = 0; ni < 4; ni++) {
                acc[mi][ni] = __builtin_amdgcn_mfma_f32_16x16x32_f16(ah[mi], bh[ni], acc[mi][ni], 0, 0, 0);
                acc[mi][ni] = __builtin_amdgcn_mfma_f32_16x16x32_f16(ah[mi], bl[ni], acc[mi][ni], 0, 0, 0);
                acc[mi][ni] = __builtin_amdgcn_mfma_f32_16x16x32_f16(al[mi], bh[ni], acc[mi][ni], 0, 0, 0);
            }
        __builtin_amdgcn_s_setprio(0);
        if (dw) writeA((k + 1) & 1, Rw);
        asm volatile("s_waitcnt vmcnt(8)" ::: "memory");
        asm volatile("s_waitcnt lgkmcnt(0)" ::: "memory");
        __builtin_amdgcn_sched_barrier(0);
        __builtin_amdgcn_s_barrier();
        __builtin_amdgcn_sched_barrier(0);
    };
    int rb = 0;
    for (int kp = 0; kp < 12; kp++) {
        int k = kp * 2;
        body(k,     rb, rb == 0 ? 2 : rb - 1, R0, R1, (k + 2) <= 24, true);
        rb = (rb == 2) ? 0 : rb + 1;
        body(k + 1, rb, rb == 0 ? 2 : rb - 1, R1, R0, (k + 3) <= 24, true);
        rb = (rb == 2) ? 0 : rb + 1;
    }
    body(24, rb, 0, R0, R1, false, false);
#pragma unroll
    for (int ni = 0; ni < 4; ni++) {
        int col = n0 + wn * 64 + ni * 16 + frow;
        float bv = bias[col];
#pragma unroll
        for (int mi = 0; mi < 4; mi++) {
            int rbase = r0 + wm * 64 + mi * 16 + fgrp * 4;
#pragma unroll
            for (int p = 0; p < 4; p++)
                C[(size_t)(rbase + p) * H_ + col] = acc[mi][ni][p] + bv;
        }
    }
}

__global__ __launch_bounds__(256, 2) void gemm1_old(
    const _Float16* __restrict__ Zh, const float* __restrict__ W1,
    const float* __restrict__ alpha, const float* __restrict__ bW,
    float* __restrict__ C)
{
    __shared__ _Float16 L[28672];
    const int tid  = threadIdx.x;
    const int gl   = (blockIdx.x & 7) * 200 + (blockIdx.x >> 3);
    const int r0   = (gl >> 2) * 128;
    const int n0   = (gl & 3) * 128;
    const int tt   = r0 >> 9;
    const int lane = tid & 63;
    const int wm = (tid >> 7) & 1, wn = (tid >> 6) & 1;
    const int frow = lane & 15, fgrp = lane >> 4;
    const int arow = tid >> 2;
    const int acol = (((tid & 3) ^ ((arow >> 1) & 3)) << 3);
    const _Float16* ZhB = Zh + (size_t)(r0 + arow) * H_ + acol;
    const int brow = tid >> 1, bhalf = tid & 1;
    const float* W1B = W1 + (size_t)(n0 + brow) * H_ + bhalf * 16;
    const float* alB = alpha + tt * H_ + bhalf * 16;
    const int boff = brow * 32;
    const int bc0  = (((bhalf * 2)     ^ ((brow >> 1) & 3)) << 3);
    const int bc1  = (((bhalf * 2 + 1) ^ ((brow >> 1) & 3)) << 3);
    f32x4 acc[4][4];
#pragma unroll
    for (int i = 0; i < 4; i++)
#pragma unroll
        for (int j = 0; j < 4; j++) acc[i][j] = f32x4{0.f, 0.f, 0.f, 0.f};
    auto stageA = [&](int sbuf, int kt) {
        _Float16* d = L + sbuf * 4096;
        gload_lds16(ZhB + kt,           d + tid * 8);
        gload_lds16(ZhB + 64 * H_ + kt, d + 2048 + tid * 8);
    };
    auto loadB = [&](float4 (&wv)[4], float4 (&av)[4], int kt) {
#pragma unroll
        for (int j = 0; j < 4; j++) {
            wv[j] = *(const float4*)(W1B + kt + j * 4);
            av[j] = *(const float4*)(alB + kt + j * 4);
        }
    };
    auto writeB = [&](int wbuf, const float4 (&wv)[4], const float4 (&av)[4]) {
        _Float16* dh = L + 12288 + wbuf * 8192;
        _Float16* dl = dh + 4096;
        const float* w = (const float*)wv;
        const float* a = (const float*)av;
        f16x8 h0, l0, h1, l1;
#pragma unroll
        for (int j = 0; j < 8; j++) {
            float p0 = a[j] * w[j];
            _Float16 q0 = (_Float16)p0;
            h0[j] = q0; l0[j] = (_Float16)(p0 - (float)q0);
            float p1 = a[8 + j] * w[8 + j];
            _Float16 q1 = (_Float16)p1;
            h1[j] = q1; l1[j] = (_Float16)(p1 - (float)q1);
        }
        *(f16x8*)(dh + boff + bc0) = h0;
        *(f16x8*)(dh + boff + bc1) = h1;
        *(f16x8*)(dl + boff + bc0) = l0;
        *(f16x8*)(dl + boff + bc1) = l1;
    };
    float4 Wv0[4], Av0[4], Wv1[4], Av1[4];
    stageA(0, 0); stageA(1, 32); loadB(Wv0, Av0, 0); loadB(Wv1, Av1, 32);
    writeB(0, Wv0, Av0);
    asm volatile("s_waitcnt lgkmcnt(0)" ::: "memory");
    __builtin_amdgcn_sched_barrier(0);
    __builtin_amdgcn_s_barrier();
    __builtin_amdgcn_sched_barrier(0);
    auto body = [&](int k, int rbuf, int sbuf, float4 (&Wl_)[4], float4 (&Al_)[4],
                    float4 (&Ww_)[4], float4 (&Aw_)[4], bool pf, bool dw) {
        if (pf) { stageA(sbuf, (k + 2) * 32); loadB(Wl_, Al_, (k + 2) * 32); }
        const _Float16* Ab = L + rbuf * 4096;
        const _Float16* Bb = L + 12288 + (k & 1) * 8192;
        f16x8 az[4], bh[4], bl[4];
#pragma unroll
        for (int mi = 0; mi < 4; mi++) {
            int row = wm * 64 + mi * 16 + frow;
            int off = row * 32 + ((fgrp ^ ((row >> 1) & 3)) << 3);
            az[mi] = *(const f16x8*)(Ab + off);
        }
#pragma unroll
        for (int ni = 0; ni < 4; ni++) {
            int row = wn * 64 + ni * 16 + frow;
            int off = row * 32 + ((fgrp ^ ((row >> 1) & 3)) << 3);
            bh[ni] = *(const f16x8*)(Bb + off);
            bl[ni] = *(const f16x8*)(Bb + 4096 + off);
        }
        __builtin_amdgcn_s_setprio(1);
#pragma unroll
        for (int mi = 0; mi < 4; mi++)
#pragma unroll
            for (int ni = 0; ni < 4; ni++) {
                acc[mi][ni] = __builtin_amdgcn_mfma_f32_16x16x32_f16(az[mi], bh[ni], acc[mi][ni], 0, 0, 0);
                acc[mi][ni] = __builtin_amdgcn_mfma_f32_16x16x32_f16(az[mi], bl[ni], acc[mi][ni], 0, 0, 0);
            }
        __builtin_amdgcn_s_setprio(0);
        if (dw) writeB((k + 1) & 1, Ww_, Aw_);
        asm volatile("s_waitcnt vmcnt(10)" ::: "memory");
        asm volatile("s_waitcnt lgkmcnt(0)" ::: "memory");
        __builtin_amdgcn_sched_barrier(0);
        __builtin_amdgcn_s_barrier();
        __builtin_amdgcn_sched_barrier(0);
    };
    int rb = 0;
    for (int kp = 0; kp < 7; kp++) {
        int k = kp * 2;
        body(k,     rb, rb == 0 ? 2 : rb - 1, Wv0, Av0, Wv1, Av1, true, true);
        rb = (rb == 2) ? 0 : rb + 1;
        body(k + 1, rb, rb == 0 ? 2 : rb - 1, Wv1, Av1, Wv0, Av0, (k + 3) <= 15, true);
        rb = (rb == 2) ? 0 : rb + 1;
    }
    body(14, rb, 0, Wv0, Av0, Wv1, Av1, false, true);
    rb = 0;
    body(15, rb, 0, Wv1, Av1, Wv0, Av0, false, false);
#pragma unroll
    for (int ni = 0; ni < 4; ni++) {
        int col = n0 + wn * 64 + ni * 16 + frow;
        float bv = bW[tt * H_ + col];
#pragma unroll
        for (int mi = 0; mi < 4; mi++) {
            int rbase = r0 + wm * 64 + mi * 16 + fgrp * 4;
#pragma unroll
            for (int p = 0; p < 4; p++)
                C[(size_t)(rbase + p) * H_ + col] = acc[mi][ni][p] + bv;
        }
    }
}

// ---------------------------------------------------------------------------
// bW[t,n] = sum_f beta[t,f]*W1[n,f] + b1[n].
// ---------------------------------------------------------------------------
__global__ __launch_bounds__(512) void bw_kernel(
    const float* __restrict__ beta, const float* __restrict__ W1,
    const float* __restrict__ b1, float* __restrict__ bW)
{
    __shared__ float bs[512];
    const int t = blockIdx.x, n = threadIdx.x;
    bs[n] = beta[t * H_ + n];
    __syncthreads();
    const float* wr = W1 + (size_t)n * H_;
    float s = b1[n];
    for (int f = 0; f < H_; f += 4) {
        float4 w = *(const float4*)(wr + f);
        s = fmaf(bs[f],     w.x, s);
        s = fmaf(bs[f + 1], w.y, s);
        s = fmaf(bs[f + 2], w.z, s);
        s = fmaf(bs[f + 3], w.w, s);
    }
    bW[t * H_ + n] = s;
}

// ---------------------------------------------------------------------------
// LIF scan -> fp16 spikes (0/1 exact). Unfused rounding matches reference.
// ---------------------------------------------------------------------------
__global__ __launch_bounds__(256) void lif_kernel(
    const float* __restrict__ cur, _Float16* __restrict__ z)
{
    const int tid = blockIdx.x * 256 + threadIdx.x;   // b*512 + h
    float v = 0.f, ii = 0.f;
    const float* p = cur + tid;
    _Float16* q = z + tid;
    for (int t = 0; t < T_; t++) {
        float vd = __fadd_rn(v, __fmul_rn(0.1f, __fsub_rn(ii, v)));
        float id = __fmul_rn(ii, 0.95f);
        int zz = (vd > 1.0f) ? 1 : 0;
        v  = zz ? 0.f : vd;
        ii = __fadd_rn(id, p[(size_t)t * BH]);
        q[(size_t)t * BH] = (_Float16)zz;
    }
}

// ---------------------------------------------------------------------------
// BN stats, two-stage. Spike sums are small ints -> exact.
// ---------------------------------------------------------------------------
__global__ __launch_bounds__(512) void bn_part(const _Float16* __restrict__ z,
                                               float* __restrict__ part)
{
    const int t = blockIdx.x >> 3, c = blockIdx.x & 7, h = threadIdx.x;
    const _Float16* p = z + (size_t)t * BH + (size_t)(c * 64) * H_ + h;
    float fs = 0.f;
    for (int b = 0; b < 64; b++) fs += (float)p[(size_t)b * H_];
    part[(size_t)blockIdx.x * H_ + h] = fs;
}

__global__ __launch_bounds__(512) void bn_fin(const float* __restrict__ part,
                          const float* __restrict__ g, const float* __restrict__ bt,
                          float* __restrict__ alpha, float* __restrict__ beta)
{
    const int t = blockIdx.x, h = threadIdx.x;
    float fs = 0.f;
#pragma unroll
    for (int c = 0; c < 8; c++) fs += part[(size_t)(t * 8 + c) * H_ + h];
    float m   = fs * (1.0f / 512.0f);
    float var = __fsub_rn(m, __fmul_rn(m, m));
    float al  = g[h] / sqrtf(__fadd_rn(var, 1e-5f));
    float be  = __fsub_rn(bt[h], __fmul_rn(m, al));
    alpha[t * H_ + h] = al;
    beta [t * H_ + h] = be;
}

// ---------------------------------------------------------------------------
// U = (alpha1*Z1+beta1) @ Wo^T  — one wave per row.
// ---------------------------------------------------------------------------
__global__ __launch_bounds__(256) void ugemm_kernel(
    const _Float16* __restrict__ Z, const float* __restrict__ alpha,
    const float* __restrict__ beta, const float* __restrict__ Wo,
    float* __restrict__ U)
{
    const int tid  = threadIdx.x;
    const int wave = tid >> 6, lane = tid & 63;
    const size_t r = (size_t)blockIdx.x * 4 + wave;
    const int t = (int)(r >> 9);
    const _Float16* zr = Z + r * 512;
    const float* alp = alpha + t * 512;
    const float* bet = beta  + t * 512;
    float acc[NOUT_];
#pragma unroll
    for (int o = 0; o < NOUT_; o++) acc[o] = 0.f;
#pragma unroll
    for (int jj = 0; jj < 8; jj++) {
        int j = jj * 64 + lane;
        float h = fmaf((float)zr[j], alp[j], bet[j]);
#pragma unroll
        for (int o = 0; o < NOUT_; o++) acc[o] = fmaf(h, Wo[o * 512 + j], acc[o]);
    }
#pragma unroll
    for (int o = 0; o < NOUT_; o++) {
        float v = acc[o];
#pragma unroll
        for (int off = 32; off; off >>= 1) v += __shfl_down(v, off, 64);
        if (lane == 0) U[r * NOUT_ + o] = v;
    }
}

// ---------------------------------------------------------------------------
// Output leaky integrator.
// ---------------------------------------------------------------------------
__global__ void li_kernel(const float* __restrict__ U, float* __restrict__ out)
{
    const int tid = blockIdx.x * 256 + threadIdx.x;   // b*10 + o
    if (tid >= B_ * NOUT_) return;
    float vo = 0.f, io = 0.f;
    for (int t = 0; t < T_; t++) {
        vo = __fadd_rn(vo, __fmul_rn(0.1f, __fsub_rn(io, vo)));
        out[t * (B_ * NOUT_) + tid] = vo;
        io = __fadd_rn(__fmul_rn(io, 0.95f), U[t * (B_ * NOUT_) + tid]);
    }
}

// ---------------------------------------------------------------------------
extern "C" void kernel_launch(void* const* d_in, const int* in_sizes, int n_in,
                              void* d_out, int out_size, void* d_ws, size_t ws_size,
                              hipStream_t stream)
{
    const float* X   = (const float*)d_in[0];
    const float* W0  = (const float*)d_in[1];
    const float* b0  = (const float*)d_in[2];
    const float* W1  = (const float*)d_in[3];
    const float* b1  = (const float*)d_in[4];
    const float* g0  = (const float*)d_in[5];
    const float* bt0 = (const float*)d_in[6];
    const float* g1  = (const float*)d_in[7];
    const float* bt1 = (const float*)d_in[8];
    const float* Wo  = (const float*)d_in[9];
    float* out = (float*)d_out;

    char* w = (char*)d_ws;
    const size_t NEED = 327475200ull;

    if (ws_size >= NEED) {
        // layout: CUR | Zh | XA(Xh->Wfh) | XB(Xl->Wfl) | alphas/betas/bW | U | W0h/l | part
        float*    CUR    = (float*)w;                           // 104,857,600
        _Float16* Zh     = (_Float16*)(w + 104857600);          //  52,428,800
        _Float16* XA     = (_Float16*)(w + 157286400);          //  81,920,000
        _Float16* XB     = (_Float16*)(w + 239206400);          //  81,920,000
        float*    alpha0 = (float*)(w + 321126400);
        float*    beta0  = alpha0 + T_*H_;
        float*    alpha1 = beta0  + T_*H_;
        float*    beta1  = alpha1 + T_*H_;
        float*    bW     = beta1  + T_*H_;
        float*    U      = bW     + T_*H_;
        _Float16* W0h    = (_Float16*)(U + R_*NOUT_);
        _Float16* W0l    = W0h + 512*FP_;
        float*    part   = (float*)(W0l + 512*FP_);

        convX_kernel<<<20000, 256, 0, stream>>>(X, XA, XB);
        convW_kernel<<<(512*FP_+255)/256, 256, 0, stream>>>(W0, W0h, W0l, F_, FP_, 512*FP_);
        gemm0_mfma  <<<1600,  256, 0, stream>>>(XA, XB, W0h, W0l, b0, CUR);
        lif_kernel  <<<1024,  256, 0, stream>>>(CUR, Zh);                    // -> Z0
        bn_part     <<<800,   512, 0, stream>>>(Zh, part);
        bn_fin      <<<100,   512, 0, stream>>>(part, g0, bt0, alpha0, beta0);
        bw_kernel   <<<100,   512, 0, stream>>>(beta0, W1, b1, bW);
        foldW1_kernel<<<12800,256, 0, stream>>>(W1, alpha0, XA, XB);         // Xh/Xl dead
        gemm1_mfma  <<<1600,  256, 0, stream>>>(Zh, XA, XB, bW, CUR);
        lif_kernel  <<<1024,  256, 0, stream>>>(CUR, Zh);                    // -> Z1
        bn_part     <<<800,   512, 0, stream>>>(Zh, part);
        bn_fin      <<<100,   512, 0, stream>>>(part, g1, bt1, alpha1, beta1);
        ugemm_kernel<<<12800, 256, 0, stream>>>(Zh, alpha1, beta1, Wo, U);
        li_kernel   <<<20,    256, 0, stream>>>(U, out);
    } else {
        // round-4 fallback layout (~164 MB)
        float*    CUR    = (float*)w;
        _Float16* Zh     = (_Float16*)(w + 104857600);
        float*    alpha0 = (float*)(w + 104857600 + 52428800);
        float*    beta0  = alpha0 + T_*H_;
        float*    alpha1 = beta0  + T_*H_;
        float*    beta1  = alpha1 + T_*H_;
        float*    bW     = beta1  + T_*H_;
        float*    U      = bW     + T_*H_;
        _Float16* W0h    = (_Float16*)(U + R_*NOUT_);
        _Float16* W0l    = W0h + 512*FP_;
        float*    part   = (float*)(W0l + 512*FP_);

        convW_kernel<<<(512*FP_+255)/256, 256, 0, stream>>>(W0, W0h, W0l, F_, FP_, 512*FP_);
        gemm0_old   <<<1600,  256, 0, stream>>>(X, W0h, W0l, b0, CUR);
        lif_kernel  <<<1024,  256, 0, stream>>>(CUR, Zh);
        bn_part     <<<800,   512, 0, stream>>>(Zh, part);
        bn_fin      <<<100,   512, 0, stream>>>(part, g0, bt0, alpha0, beta0);
        bw_kernel   <<<100,   512, 0, stream>>>(beta0, W1, b1, bW);
        gemm1_old   <<<1600,  256, 0, stream>>>(Zh, W1, alpha0, bW, CUR);
        lif_kernel  <<<1024,  256, 0, stream>>>(CUR, Zh);
        bn_part     <<<800,   512, 0, stream>>>(Zh, part);
        bn_fin      <<<100,   512, 0, stream>>>(part, g1, bt1, alpha1, beta1);
        ugemm_kernel<<<12800, 256, 0, stream>>>(Zh, alpha1, beta1, Wo, U);
        li_kernel   <<<20,    256, 0, stream>>>(U, out);
    }
}